// Round 10
// baseline (85.962 us; speedup 1.0000x reference)
//
#include <hip/hip_runtime.h>
#include <hip/hip_bf16.h>
#include <math.h>

// Chamfer distance via MFMA, fp16 quantized / fp32 accumulate.
// K-packing: A_row = (-2ax,-2ay,-2az, 1, sqa, 0...), B_col = (bx,by,bz, sqb, 1, 0...)
// => MFMA dot = sqa + sqb - 2 a.b = full squared distance (from quantized coords).
// R10 vs R9: shape 32x32x16 -> 16x16x32. Result regs per MFMA drop 16->4, so a
// 4-deep pipeline + rowmin is ~55 live VGPRs -> __launch_bounds__(256,8) = 8
// waves/SIMD (2x all prior rounds) to break the phase-aligned stall pattern.
// K=32 layout: only quad-0 lanes carry A data (k=0..7 slots); quads 1-3 have
// A=0 so their (broadcast) B reads are don't-care -> NO lane predication at all.

typedef _Float16 half8    __attribute__((ext_vector_type(8)));
typedef float    floatx4  __attribute__((ext_vector_type(4)));

constexpr int CH   = 2048;     // B points per block chunk (16 KB LDS)
constexpr int WR   = 16;       // rows per wave (16x16 tile)
constexpr int ROWS = 64;       // 4 waves * 16 rows
constexpr int BLK  = 256;

// ---- pack both clouds into f16 fragments (x,y,z,|p|^2), padded to NP ----
__global__ __launch_bounds__(256) void pack_kernel(
    const float* __restrict__ P1, const float* __restrict__ P2,
    uint2* __restrict__ F1, uint2* __restrict__ F2,
    int n1, int n2, int NP, float* __restrict__ out)
{
    int i = blockIdx.x * 256 + threadIdx.x;
    if (i == 0) out[0] = 0.0f;           // zeroed before reduce runs (stream order)
    const float* P; uint2* F; int n, idx;
    if (i < NP)          { P = P1; F = F1; n = n1; idx = i; }
    else if (i < 2 * NP) { P = P2; F = F2; n = n2; idx = i - NP; }
    else return;
    int j = idx < n ? idx : n - 1;       // pad with dup of last point: min-safe
    float x = P[3*j], y = P[3*j+1], z = P[3*j+2];
    _Float16 hx = (_Float16)x, hy = (_Float16)y, hz = (_Float16)z;
    float qx = (float)hx, qy = (float)hy, qz = (float)hz;
    _Float16 hw = (_Float16)(qx*qx + qy*qy + qz*qz);
    union { _Float16 h[4]; uint2 u; } p;
    p.h[0] = hx; p.h[1] = hy; p.h[2] = hz; p.h[3] = hw;
    F[idx] = p.u;
}

__global__ __launch_bounds__(BLK, 8) void chamfer_sweep_kernel(
    const uint2* __restrict__ F1, const uint2* __restrict__ F2,
    float* __restrict__ part, int n1, int n2, int YC)
{
    __shared__ uint2 sB[CH];          // pre-packed fragments, straight copy
    __shared__ float sRowMin[ROWS];

    const int dir   = blockIdx.z;
    const uint2* FA = dir == 0 ? F1 : F2;
    const uint2* FB = dir == 0 ? F2 : F1;
    const int nA    = dir == 0 ? n1 : n2;
    float* pbase    = part + (dir == 0 ? 0 : (size_t)YC * n1);

    const int tid  = threadIdx.x;
    const int wave = tid >> 6;
    const int lane = tid & 63;
    const int n    = lane & 15;    // col within 16-wide tile / row within A-tile
    const int quad = lane >> 4;    // k-group: quad q holds k = q*8 .. q*8+7

    // ---- stage: pure 16KB copy, 16B granules (no math, coalesced) ----
    {
        const uint4* src = (const uint4*)(FB + (size_t)blockIdx.y * CH);
        uint4* dst = (uint4*)sB;
        for (int i = tid; i < CH / 2; i += BLK) dst[i] = src[i];
    }

    // ---- A fragment: rows m = lane&15; only quad 0 (k=0..7) carries data ----
    const _Float16 h0 = (_Float16)0.0f;
    const bool q0 = (quad == 0);
    half8 af;
    {
        int arow = blockIdx.x * ROWS + wave * WR + n;   // < NP by construction
        union { uint2 u; _Float16 h[4]; } au; au.u = FA[arow];
        const _Float16 m2 = (_Float16)(-2.0f);
        af[0] = q0 ? (_Float16)(au.h[0] * m2) : h0;
        af[1] = q0 ? (_Float16)(au.h[1] * m2) : h0;
        af[2] = q0 ? (_Float16)(au.h[2] * m2) : h0;
        af[3] = q0 ? (_Float16)1.0f : h0;
        af[4] = q0 ? au.h[3] : h0;
        af[5] = h0; af[6] = h0; af[7] = h0;
    }

    __syncthreads();

    float rm0 = 1e30f, rm1 = 1e30f, rm2 = 1e30f, rm3 = 1e30f;
    const floatx4 zacc = {};

    // Persistent B-operand quads: upper pair (1.0h,0 | 0,0) written ONCE;
    // per-iter ds_read_b64 lands directly in the lower pair. Quads 1-3 read
    // the same addresses (broadcast) — their content is don't-care (A=0 there).
    union BF { half8 v; unsigned u[4]; uint2 lo; };
    BF bu0, bu1, bu2, bu3;
    { union { _Float16 h[2]; unsigned u; } q;
      q.h[0] = (_Float16)1.0f; q.h[1] = h0;
      bu0.u[2] = q.u; bu0.u[3] = 0u;
      bu1.u[2] = q.u; bu1.u[3] = 0u;
      bu2.u[2] = q.u; bu2.u[3] = 0u;
      bu3.u[2] = q.u; bu3.u[3] = 0u; }

    // ---- main sweep: 4 col-tiles (64 points) per iteration, 4 MFMAs ----
    for (int bt = 0; bt < CH / 64; ++bt) {
        const uint2* p = sB + bt * 64 + n;
        bu0.lo = p[0];
        bu1.lo = p[16];
        bu2.lo = p[32];
        bu3.lo = p[48];

        floatx4 d0 = __builtin_amdgcn_mfma_f32_16x16x32_f16(af, bu0.v, zacc, 0, 0, 0);
        floatx4 d1 = __builtin_amdgcn_mfma_f32_16x16x32_f16(af, bu1.v, zacc, 0, 0, 0);
        floatx4 d2 = __builtin_amdgcn_mfma_f32_16x16x32_f16(af, bu2.v, zacc, 0, 0, 0);
        floatx4 d3 = __builtin_amdgcn_mfma_f32_16x16x32_f16(af, bu3.v, zacc, 0, 0, 0);

        float t0 = fminf(fminf(rm0, d0[0]), d1[0]);   // v_min3 pairs
        float t1 = fminf(fminf(rm1, d0[1]), d1[1]);
        float t2 = fminf(fminf(rm2, d0[2]), d1[2]);
        float t3 = fminf(fminf(rm3, d0[3]), d1[3]);
        rm0 = fminf(fminf(t0, d2[0]), d3[0]);
        rm1 = fminf(fminf(t1, d2[1]), d3[1]);
        rm2 = fminf(fminf(t2, d2[2]), d3[2]);
        rm3 = fminf(fminf(t3, d2[3]), d3[3]);
    }

    // ---- epilogue: reduce across the 16 cols (xor-shuffle, masks 1..8) ----
#pragma unroll
    for (int mask = 1; mask <= 8; mask <<= 1) {
        rm0 = fminf(rm0, __shfl_xor(rm0, mask));
        rm1 = fminf(rm1, __shfl_xor(rm1, mask));
        rm2 = fminf(rm2, __shfl_xor(rm2, mask));
        rm3 = fminf(rm3, __shfl_xor(rm3, mask));
    }
    if (n == 0) {   // C/D row map: row = quad*4 + reg
        sRowMin[wave * WR + quad * 4 + 0] = rm0;
        sRowMin[wave * WR + quad * 4 + 1] = rm1;
        sRowMin[wave * WR + quad * 4 + 2] = rm2;
        sRowMin[wave * WR + quad * 4 + 3] = rm3;
    }
    __syncthreads();

    if (tid < ROWS) {   // one partial slot per (dir,row,ychunk) — no atomics
        int grow = blockIdx.x * ROWS + tid;
        if (grow < nA) pbase[(size_t)grow * YC + blockIdx.y] = sRowMin[tid];
    }
}

// Per-row min over YC contiguous partials -> sqrt -> block sum -> atomicAdd(out)
__global__ __launch_bounds__(256) void reduce_kernel(
    const float* __restrict__ part, float* __restrict__ out,
    int ntot, int YC)
{
    __shared__ float s[256];
    int r = blockIdx.x * 256 + threadIdx.x;
    float acc = 0.0f;
    if (r < ntot) {
        float m;
        if (YC == 8) {   // fast path: two 16B loads
            const float4* pv = (const float4*)(part + (size_t)r * 8);
            float4 a = pv[0], b = pv[1];
            m = fminf(fminf(fminf(a.x, a.y), fminf(a.z, a.w)),
                      fminf(fminf(b.x, b.y), fminf(b.z, b.w)));
        } else {
            const float* p = part + (size_t)r * YC;
            m = 1e30f;
            for (int y = 0; y < YC; ++y) m = fminf(m, p[y]);
        }
        acc = sqrtf(fmaxf(m, 0.0f));
    }
    s[threadIdx.x] = acc;
    __syncthreads();
    for (int w = 128; w > 0; w >>= 1) {
        if (threadIdx.x < w) s[threadIdx.x] += s[threadIdx.x + w];
        __syncthreads();
    }
    if (threadIdx.x == 0) atomicAdd(out, s[0]);
}

extern "C" void kernel_launch(void* const* d_in, const int* in_sizes, int n_in,
                              void* d_out, int out_size, void* d_ws, size_t ws_size,
                              hipStream_t stream) {
    const float* P1 = (const float*)d_in[0];
    const float* P2 = (const float*)d_in[1];
    const int n1 = in_sizes[0] / 3;   // 16384
    const int n2 = in_sizes[1] / 3;   // 16384
    const int nmax = (n1 > n2) ? n1 : n2;
    const int YC = (nmax + CH - 1) / CH;          // y-chunks (8)
    const int NP = YC * CH;                       // padded point count (16384)

    uint2* F1   = (uint2*)d_ws;                   // packed fragments, cloud 1
    uint2* F2   = F1 + NP;                        // packed fragments, cloud 2
    float* part = (float*)(F2 + NP);              // [(n1+n2) * YC] partial row-mins
    float* out  = (float*)d_out;

    pack_kernel<<<(2 * NP + 255) / 256, 256, 0, stream>>>(P1, P2, F1, F2, n1, n2, NP, out);

    {   // two independent sweeps (z = direction), pure register row-mins
        dim3 grid(NP / ROWS, YC, 2);
        chamfer_sweep_kernel<<<grid, BLK, 0, stream>>>(F1, F2, part, n1, n2, YC);
    }
    reduce_kernel<<<(n1 + n2 + 255) / 256, 256, 0, stream>>>(part, out, n1 + n2, YC);
}